// Round 2
// baseline (32793.588 us; speedup 1.0000x reference)
//
#include <hip/hip_runtime.h>
#include <math.h>

#define SN 512
#define BN 128
#define HN 256
#define G4 1024
#define NSLICE 16   // slices per sample-group
#define NGRP   16   // sample groups
#define SBG    8    // samples per group

// ---- workspace layout (float offsets) ----
#define OFF_EPT    ((size_t)0)                       // enc_proj^T [256][512]
#define OFF_XPROJ  (OFF_EPT   + (size_t)131072)      // X_proj [512][1024]
#define OFF_WIHT   (OFF_XPROJ + (size_t)524288)      // W_ih^T [256][1024]
#define OFF_XT     (OFF_WIHT  + (size_t)262144)      // x^T [256][512]
#define OFF_BIAS   (OFF_XT    + (size_t)131072)      // b_ih+b_hh [1024]
#define OFF_IPROJ  (OFF_BIAS  + (size_t)1024)        // W_ih@init_dec [1024]
#define OFF_HEX    (OFF_IPROJ + (size_t)1024)        // h exchange [16][8*256]
#define OFF_WAEX   (OFF_HEX   + (size_t)32768)       // hWa exchange [16][8*256]
#define OFF_LEX    (OFF_WAEX  + (size_t)32768)       // logits exchange [16][8*512]
#define OFF_BAR    (OFF_LEX   + (size_t)65536)       // barriers [16][1536] ints
#define BAR_INTS   (16*1536)
// total = 1206272 floats = 4.83 MB

// ---- dynamic LDS layout (byte offsets), 16B aligned ----
#define L_UNION 0        // 36864 B: pb f32[8][64][9] / pp3 f64[32][16][9] / pf f64[16][32][9]
#define L_VLD   36864    // 2048 B: v as f64 [256]
#define L_ES    38912    // 32768 B: ept slice [256][32]
#define L_WAD   71680    // 16384 B: Wa_dec slice [256][16]
#define L_HF    88064    // 8320 B: h full [8][260]
#define L_HWF   96384    // 8320 B: hWa full [8][260]
#define L_XPRO  104704   // 2048 B: x-proj rows [8][64]
#define L_MASK  106752   // 1024 B: mask chunk [32][8]
#define L_CL    107776   // 512 B: c chunk [16][8]
#define L_BIAS  108288   // 256 B: bias rows [64]
#define L_SEL   108544   // 32 B: selected idx [8]
#define SMEM_TOTAL 108576

__device__ __forceinline__ float tanh_fast(float x) {
    float a = fabsf(x);
    float e = __builtin_amdgcn_exp2f(a * -2.8853900817779268f);
    float r = (1.0f - e) * __builtin_amdgcn_rcpf(1.0f + e);
    return copysignf(r, x);
}

// ---------------- init kernel 1: transposes + bias + barrier zero ----------------
__global__ __launch_bounds__(256) void k_init_transpose(
    const float* __restrict__ Wih, const float* __restrict__ bih,
    const float* __restrict__ bhh, const float* __restrict__ x,
    float* __restrict__ ws)
{
    float* wiht = ws + OFF_WIHT;
    float* xt   = ws + OFF_XT;
    float* bias = ws + OFF_BIAS;
    int*   bar  = (int*)(ws + OFF_BAR);
    int i = blockIdx.x * 256 + threadIdx.x;
    if (i < 262144) {                        // W_ih^T [e][r]
        int e = i >> 10, r = i & 1023;
        wiht[i] = Wih[(size_t)r * 256 + e];
    } else if (i < 393216) {                 // x^T [e][s]
        int j = i - 262144; int e = j >> 9, s = j & 511;
        xt[j] = x[(size_t)s * 256 + e];
    } else if (i < 394240) {                 // bias
        int j = i - 393216;
        bias[j] = bih[j] + bhh[j];
    } else if (i < 394240 + BAR_INTS) {      // zero barriers
        bar[i - 394240] = 0;
    }
}

// ---------------- init kernel 2: projections (double-accum) ----------------
__global__ __launch_bounds__(512) void k_init_proj(
    const float* __restrict__ x, const float* __restrict__ Wae,
    const float* __restrict__ ba, const float* __restrict__ idec,
    float* __restrict__ ws)
{
    const float* wiht = ws + OFF_WIHT;
    const float* xt   = ws + OFF_XT;
    float* ept   = ws + OFF_EPT;
    float* xproj = ws + OFF_XPROJ;
    float* iproj = ws + OFF_IPROJ;
    int blk = blockIdx.x, tid = threadIdx.x;
    if (blk < 256) {
        int k = blk, s = tid;
        double a = 0.0;
        for (int e = 0; e < 256; ++e)
            a += (double)Wae[(size_t)k * 256 + e] * (double)xt[(size_t)e * 512 + s];
        ept[(size_t)k * 512 + s] = (float)((double)ba[k] + a);
    } else if (blk < 256 + 1024) {
        int idx = blk - 256;
        int s = idx >> 1;
        int r = (idx & 1) * 512 + tid;
        double a = 0.0;
        for (int e = 0; e < 256; ++e)
            a += (double)x[(size_t)s * 256 + e] * (double)wiht[(size_t)e * 1024 + r];
        xproj[(size_t)s * 1024 + r] = (float)a;
    } else {
        int r = (blk - 1280) * 512 + tid;
        double a = 0.0;
        for (int e = 0; e < 256; ++e)
            a += (double)idec[e] * (double)wiht[(size_t)e * 1024 + r];
        iproj[r] = (float)a;
    }
}

// ---------------- persistent decode: 256 WGs = 16 groups x 16 slices ----------------
__global__ __launch_bounds__(512, 2) void k_decode(
    const float* __restrict__ gmb, const float* __restrict__ vvec,
    const float* __restrict__ Whh, const float* __restrict__ Wad,
    float* __restrict__ ws, float* __restrict__ out)
{
    extern __shared__ char smem[];
    float*  pb   = (float*)(smem + L_UNION);    // [8 w][64 rl][9] (sl in 0..7)
    double* pp3  = (double*)(smem + L_UNION);   // [32 kc][16 rl][9]
    double* pf   = (double*)(smem + L_UNION);   // [16 kc][32 ss][9]
    double* vLd  = (double*)(smem + L_VLD);
    float*  es_l = (float*)(smem + L_ES);       // [k][32]
    float*  wa_l = (float*)(smem + L_WAD);      // [k][16]
    float*  hf   = (float*)(smem + L_HF);       // [8][260]
    float*  hwf  = (float*)(smem + L_HWF);      // [8][260]
    float*  xpro = (float*)(smem + L_XPRO);     // [8][64]
    float*  mask = (float*)(smem + L_MASK);     // [32 ss][8 sl]
    float*  c_l  = (float*)(smem + L_CL);       // [16 jl][8 sl]
    float*  bias_l = (float*)(smem + L_BIAS);   // [64 rl]
    int*    selA = (int*)(smem + L_SEL);        // [8]

    const int tid = threadIdx.x;
    const int g = blockIdx.x >> 4;      // sample group
    const int q = blockIdx.x & 15;      // slice

    const float* eptG   = ws + OFF_EPT;
    const float* xprojG = ws + OFF_XPROJ;
    const float* biasG  = ws + OFF_BIAS;
    const float* iprojG = ws + OFF_IPROJ;
    float* hex  = ws + OFF_HEX  + (size_t)g * 2048;   // [sl][256]
    float* waex = ws + OFF_WAEX + (size_t)g * 2048;   // [sl][256]
    float* lex  = ws + OFF_LEX  + (size_t)g * 4096;   // [sl][512]
    int*   barI = (int*)(ws + OFF_BAR) + (size_t)g * 1536;

    // ---- one-time LDS fills ----
    for (int i = tid; i < 8192; i += 512) {           // ept slice [k][32]
        int k = i >> 5, ss = i & 31;
        es_l[i] = eptG[(size_t)k * 512 + q * 32 + ss];
    }
    for (int i = tid; i < 4096; i += 512) {           // Wa_dec slice [k][16]
        int k = i >> 4, rl = i & 15;
        wa_l[i] = Wad[(size_t)(q * 16 + rl) * 256 + k];
    }
    for (int i = tid; i < 256; i += 512) vLd[i] = (double)vvec[i];
    if (tid < 64) bias_l[tid] = biasG[((tid >> 4) << 8) + q * 16 + (tid & 15)];
    for (int i = tid; i < 256; i += 512) mask[i] = 0.f;
    for (int i = tid; i < 128; i += 512) c_l[i] = 0.f;
    for (int i = tid; i < 2080; i += 512) { hf[i] = 0.f; hwf[i] = 0.f; }
    {   // xpro at t=0 from iproj
        int sl = tid >> 6, rl = tid & 63;
        int rg = ((rl >> 4) << 8) + q * 16 + (rl & 15);
        xpro[sl * 64 + rl] = iprojG[rg];
    }

    // ---- W_hh slice into registers: thread (w=kslice, rl=row-local), 32 weights ----
    const int w = tid >> 6, lane = tid & 63;
    const int rl1 = lane;
    const int rg1 = ((rl1 >> 4) << 8) + q * 16 + (rl1 & 15);
    const int kbase = w * 32;
    float wreg[32];
    {
        const float4* wrow = (const float4*)(Whh + (size_t)rg1 * 256 + kbase);
        #pragma unroll
        for (int j = 0; j < 8; ++j) {
            float4 v4 = wrow[j];
            wreg[4 * j + 0] = v4.x; wreg[4 * j + 1] = v4.y;
            wreg[4 * j + 2] = v4.z; wreg[4 * j + 3] = v4.w;
        }
    }
    __syncthreads();

    float lps = 0.f;

    for (int t = 0; t < SN; ++t) {
        int* barp = barI + t * 3;

        // ---- phase 1: gate partials over this thread's 32-k slice, 8 samples ----
        #pragma unroll
        for (int sl = 0; sl < 8; ++sl) {
            float a = 0.f;
            #pragma unroll
            for (int g4 = 0; g4 < 8; ++g4) {
                float4 h4 = *(const float4*)(hf + sl * 260 + kbase + 4 * g4);
                a = fmaf(wreg[4 * g4 + 0], h4.x, a);
                a = fmaf(wreg[4 * g4 + 1], h4.y, a);
                a = fmaf(wreg[4 * g4 + 2], h4.z, a);
                a = fmaf(wreg[4 * g4 + 3], h4.w, a);
            }
            pb[w * 576 + rl1 * 9 + sl] = a;
        }
        __syncthreads();

        // ---- phase 2: reduce gates + LSTM (128 threads: jl x sl) ----
        if (tid < 128) {
            int jl = tid >> 3, sl = tid & 7;
            float gv[4];
            #pragma unroll
            for (int gate = 0; gate < 4; ++gate) {
                int rl = gate * 16 + jl;
                float p0 = pb[0 * 576 + rl * 9 + sl], p1 = pb[1 * 576 + rl * 9 + sl];
                float p2 = pb[2 * 576 + rl * 9 + sl], p3 = pb[3 * 576 + rl * 9 + sl];
                float p4 = pb[4 * 576 + rl * 9 + sl], p5 = pb[5 * 576 + rl * 9 + sl];
                float p6 = pb[6 * 576 + rl * 9 + sl], p7 = pb[7 * 576 + rl * 9 + sl];
                float s8 = ((p0 + p1) + (p2 + p3)) + ((p4 + p5) + (p6 + p7));
                gv[gate] = bias_l[rl] + xpro[sl * 64 + rl] + s8;
            }
            float si = 1.0f / (1.0f + expf(-gv[0]));
            float sf = 1.0f / (1.0f + expf(-gv[1]));
            float so = 1.0f / (1.0f + expf(-gv[3]));
            float cf = sf * c_l[jl * 8 + sl] + si * tanhf(gv[2]);
            float hn = so * tanhf(cf);
            c_l[jl * 8 + sl] = cf;
            hex[sl * 256 + q * 16 + jl] = hn;
        }
        __syncthreads();
        if (tid == 0) {   // barrier B1
            __threadfence();
            __hip_atomic_fetch_add(barp + 0, 1, __ATOMIC_RELEASE, __HIP_MEMORY_SCOPE_AGENT);
            while (__hip_atomic_load(barp + 0, __ATOMIC_ACQUIRE, __HIP_MEMORY_SCOPE_AGENT) < NSLICE)
                __builtin_amdgcn_s_sleep(2);
            __threadfence();
        }
        __syncthreads();
        {   // gather full h
            int idx = tid * 4; int sl = idx >> 8, j = idx & 255;
            float4 v4 = *(const float4*)(hex + sl * 256 + j);
            *(float4*)(hf + sl * 260 + j) = v4;
        }
        __syncthreads();

        // ---- phase 3: hWa partials (thread: kc in 0..31 of 8 k, rl in 0..15) ----
        {
            int kc = tid >> 4, rl = tid & 15;
            float w3[8];
            #pragma unroll
            for (int kk = 0; kk < 8; ++kk) w3[kk] = wa_l[(kc * 8 + kk) * 16 + rl];
            #pragma unroll
            for (int sl = 0; sl < 8; ++sl) {
                double a = 0.0;
                #pragma unroll
                for (int kk = 0; kk < 8; ++kk)
                    a += (double)w3[kk] * (double)hf[sl * 260 + kc * 8 + kk];
                pp3[kc * 144 + rl * 9 + sl] = a;
            }
        }
        __syncthreads();
        if (tid < 128) {
            int rl = tid >> 3, sl = tid & 7;
            double s = 0.0;
            for (int kc = 0; kc < 32; ++kc) s += pp3[kc * 144 + rl * 9 + sl];
            waex[sl * 256 + q * 16 + rl] = (float)s;
        }
        __syncthreads();
        if (tid == 0) {   // barrier B2
            __threadfence();
            __hip_atomic_fetch_add(barp + 1, 1, __ATOMIC_RELEASE, __HIP_MEMORY_SCOPE_AGENT);
            while (__hip_atomic_load(barp + 1, __ATOMIC_ACQUIRE, __HIP_MEMORY_SCOPE_AGENT) < NSLICE)
                __builtin_amdgcn_s_sleep(2);
            __threadfence();
        }
        __syncthreads();
        {   // gather full hWa
            int idx = tid * 4; int sl = idx >> 8, j = idx & 255;
            float4 v4 = *(const float4*)(waex + sl * 256 + j);
            *(float4*)(hwf + sl * 260 + j) = v4;
        }
        __syncthreads();

        // ---- phase 4: attention partials (thread: kc4 in 0..15 of 16 k, ss in 0..31) ----
        {
            int kc4 = tid >> 5, ss = tid & 31;
            float ev[16]; double vd[16];
            #pragma unroll
            for (int kk = 0; kk < 16; ++kk) {
                ev[kk] = es_l[(kc4 * 16 + kk) * 32 + ss];
                vd[kk] = vLd[kc4 * 16 + kk];
            }
            #pragma unroll
            for (int sl = 0; sl < 8; ++sl) {
                float hw[16];
                #pragma unroll
                for (int j = 0; j < 4; ++j) {
                    float4 h4 = *(const float4*)(hwf + sl * 260 + kc4 * 16 + 4 * j);
                    hw[4 * j + 0] = h4.x; hw[4 * j + 1] = h4.y;
                    hw[4 * j + 2] = h4.z; hw[4 * j + 3] = h4.w;
                }
                double a = 0.0;
                #pragma unroll
                for (int kk = 0; kk < 16; ++kk) {
                    float tt = tanh_fast(ev[kk] + hw[kk]);
                    a += vd[kk] * (double)tt;
                }
                pf[kc4 * 288 + ss * 9 + sl] = a;
            }
        }
        __syncthreads();
        if (tid < 256) {   // reduce + logits + mask
            int ss = tid >> 3, sl = tid & 7;
            double u = 0.0;
            for (int kc = 0; kc < 16; ++kc) u += pf[kc * 288 + ss * 9 + sl];
            float lg = (float)(10.0 * tanh(u));
            lex[sl * 512 + q * 32 + ss] = lg + mask[ss * 8 + sl];
        }
        __syncthreads();
        if (tid == 0) {   // barrier B3
            __threadfence();
            __hip_atomic_fetch_add(barp + 2, 1, __ATOMIC_RELEASE, __HIP_MEMORY_SCOPE_AGENT);
            while (__hip_atomic_load(barp + 2, __ATOMIC_ACQUIRE, __HIP_MEMORY_SCOPE_AGENT) < NSLICE)
                __builtin_amdgcn_s_sleep(2);
            __threadfence();
        }
        __syncthreads();

        // ---- phase 5: exact flat log-softmax + Gumbel argmax; wave w <-> sample w ----
        {
            int sl = w;
            const float* lrow = lex + sl * 512;
            const float* grow = gmb + (size_t)t * (BN * SN) + (size_t)(g * 8 + sl) * SN;
            float lv[8];
            float M = -INFINITY;
            #pragma unroll
            for (int j = 0; j < 8; ++j) { lv[j] = lrow[lane + 64 * j]; M = fmaxf(M, lv[j]); }
            #pragma unroll
            for (int off = 32; off >= 1; off >>= 1) M = fmaxf(M, __shfl_xor(M, off, 64));
            float se = 0.f;
            #pragma unroll
            for (int j = 0; j < 8; ++j) se += expf(lv[j] - M);
            #pragma unroll
            for (int off = 32; off >= 1; off >>= 1) se += __shfl_xor(se, off, 64);
            float logS = logf(se);
            float best = -INFINITY; int bidx = 0x7fffffff; float blp = 0.f;
            #pragma unroll
            for (int j = 0; j < 8; ++j) {
                int s = lane + 64 * j;
                float lp = (lv[j] - M) - logS;
                float cd = lp + grow[s];
                if (cd > best || (cd == best && s < bidx)) { best = cd; bidx = s; blp = lp; }
            }
            #pragma unroll
            for (int off = 32; off >= 1; off >>= 1) {
                float ob = __shfl_xor(best, off, 64);
                int   oi = __shfl_xor(bidx, off, 64);
                float ol = __shfl_xor(blp, off, 64);
                if (ob > best || (ob == best && oi < bidx)) { best = ob; bidx = oi; blp = ol; }
            }
            lps += blp;
            if (lane == 0) {
                selA[sl] = bidx;
                if (q == 0) out[(size_t)(g * 8 + sl) * SN + t] = (float)bidx;
            }
        }
        __syncthreads();
        // ---- mask update + next-step xpro gather ----
        if (tid < 256) {
            int ss = tid >> 3, sl = tid & 7;
            if (selA[sl] == q * 32 + ss) mask[ss * 8 + sl] = -INFINITY;
        }
        {
            int sl = tid >> 6, rl = tid & 63;
            int rg = ((rl >> 4) << 8) + q * 16 + (rl & 15);
            xpro[sl * 64 + rl] = xprojG[(size_t)selA[sl] * 1024 + rg];
        }
        __syncthreads();
    }
    if (q == 0 && lane == 0) out[(size_t)BN * SN + g * 8 + w] = lps;
}

extern "C" void kernel_launch(void* const* d_in, const int* in_sizes, int n_in,
                              void* d_out, int out_size, void* d_ws, size_t ws_size,
                              hipStream_t stream)
{
    const float* x    = (const float*)d_in[0];
    const float* gmb  = (const float*)d_in[1];
    const float* Wih  = (const float*)d_in[2];
    const float* Whh  = (const float*)d_in[3];
    const float* bih  = (const float*)d_in[4];
    const float* bhh  = (const float*)d_in[5];
    const float* Wad  = (const float*)d_in[6];
    const float* Wae  = (const float*)d_in[7];
    const float* ba   = (const float*)d_in[8];
    const float* vvec = (const float*)d_in[9];
    const float* idec = (const float*)d_in[10];
    float* ws = (float*)d_ws;
    float* out = (float*)d_out;

    static bool attr_set = false;
    (void)attr_set;
    hipFuncSetAttribute(reinterpret_cast<const void*>(k_decode),
                        hipFuncAttributeMaxDynamicSharedMemorySize, SMEM_TOTAL);

    hipLaunchKernelGGL(k_init_transpose, dim3(1636), dim3(256), 0, stream,
                       Wih, bih, bhh, x, ws);
    hipLaunchKernelGGL(k_init_proj, dim3(1282), dim3(512), 0, stream,
                       x, Wae, ba, idec, ws);
    hipLaunchKernelGGL(k_decode, dim3(256), dim3(512), SMEM_TOTAL, stream,
                       gmb, vvec, Whh, Wad, ws, out);
}

// Round 3
// 13957.701 us; speedup vs baseline: 2.3495x; 2.3495x over previous
//
#include <hip/hip_runtime.h>
#include <math.h>

#define SN 512
#define BN 128
#define HN 256
#define G4 1024
#define NSLICE 16   // slices per sample-group
#define NGRP   16   // sample groups
#define SBG    8    // samples per group

// ---- workspace layout (float offsets) ----
#define OFF_EPT    ((size_t)0)                       // enc_proj^T [256][512]
#define OFF_XPROJ  (OFF_EPT   + (size_t)131072)      // X_proj [512][1024]
#define OFF_WIHT   (OFF_XPROJ + (size_t)524288)      // W_ih^T [256][1024]
#define OFF_XT     (OFF_WIHT  + (size_t)262144)      // x^T [256][512]
#define OFF_BIAS   (OFF_XT    + (size_t)131072)      // b_ih+b_hh [1024]
#define OFF_IPROJ  (OFF_BIAS  + (size_t)1024)        // W_ih@init_dec [1024]
#define OFF_HEX    (OFF_IPROJ + (size_t)1024)        // h exchange [16][8*256]
#define OFF_WAEX   (OFF_HEX   + (size_t)32768)       // hWa exchange [16][8*256]
#define OFF_LEX    (OFF_WAEX  + (size_t)32768)       // logits exchange [16][8*512]
#define OFF_BAR    (OFF_LEX   + (size_t)65536)       // barriers [16][1536] ints
#define BAR_INTS   (16*1536)

// ---- dynamic LDS layout (byte offsets), 16B aligned ----
#define L_UNION 0        // 36864 B: pb f32[8][64][9] / pp3 f64[32][16][9] / pf f64[16][32][9]
#define L_VLD   36864    // 2048 B: v as f64 [256]
#define L_ES    38912    // 32768 B: ept slice [256][32]
#define L_WAD   71680    // 16384 B: Wa_dec slice [256][16]
#define L_HF    88064    // 8320 B: h full [8][260]
#define L_HWF   96384    // 8320 B: hWa full [8][260]
#define L_XPRO  104704   // 2048 B: x-proj rows [8][64]
#define L_MASK  106752   // 1024 B: mask chunk [32][8]
#define L_CL    107776   // 512 B: c chunk [16][8]
#define L_BIAS  108288   // 256 B: bias rows [64]
#define L_SEL   108544   // 32 B: selected idx [8]
#define SMEM_TOTAL 108576

__device__ __forceinline__ float tanh_fast(float x) {
    float a = fabsf(x);
    float e = __builtin_amdgcn_exp2f(a * -2.8853900817779268f);
    float r = (1.0f - e) * __builtin_amdgcn_rcpf(1.0f + e);
    return copysignf(r, x);
}

__device__ __forceinline__ void st_agent(float* p, float v) {
    __hip_atomic_store(p, v, __ATOMIC_RELAXED, __HIP_MEMORY_SCOPE_AGENT);
}
__device__ __forceinline__ float ld_agent(const float* p) {
    return __hip_atomic_load(p, __ATOMIC_RELAXED, __HIP_MEMORY_SCOPE_AGENT);
}
// wave arrives: drain this wave's stores, then one relaxed add (no cache maintenance)
__device__ __forceinline__ void wave_arrive(int* cnt, int tid) {
    asm volatile("s_waitcnt vmcnt(0)" ::: "memory");
    if ((tid & 63) == 0)
        __hip_atomic_fetch_add(cnt, 1, __ATOMIC_RELAXED, __HIP_MEMORY_SCOPE_AGENT);
}
__device__ __forceinline__ void wave_poll(int* cnt, int target) {
    while (__hip_atomic_load(cnt, __ATOMIC_RELAXED, __HIP_MEMORY_SCOPE_AGENT) < target)
        __builtin_amdgcn_s_sleep(8);
    __atomic_signal_fence(__ATOMIC_SEQ_CST);
}

// ---------------- init kernel 1: transposes + bias + barrier zero ----------------
__global__ __launch_bounds__(256) void k_init_transpose(
    const float* __restrict__ Wih, const float* __restrict__ bih,
    const float* __restrict__ bhh, const float* __restrict__ x,
    float* __restrict__ ws)
{
    float* wiht = ws + OFF_WIHT;
    float* xt   = ws + OFF_XT;
    float* bias = ws + OFF_BIAS;
    int*   bar  = (int*)(ws + OFF_BAR);
    int i = blockIdx.x * 256 + threadIdx.x;
    if (i < 262144) {                        // W_ih^T [e][r]
        int e = i >> 10, r = i & 1023;
        wiht[i] = Wih[(size_t)r * 256 + e];
    } else if (i < 393216) {                 // x^T [e][s]
        int j = i - 262144; int e = j >> 9, s = j & 511;
        xt[j] = x[(size_t)s * 256 + e];
    } else if (i < 394240) {                 // bias
        int j = i - 393216;
        bias[j] = bih[j] + bhh[j];
    } else if (i < 394240 + BAR_INTS) {      // zero barriers
        bar[i - 394240] = 0;
    }
}

// ---------------- init kernel 2: projections (double-accum) ----------------
__global__ __launch_bounds__(512) void k_init_proj(
    const float* __restrict__ x, const float* __restrict__ Wae,
    const float* __restrict__ ba, const float* __restrict__ idec,
    float* __restrict__ ws)
{
    const float* wiht = ws + OFF_WIHT;
    const float* xt   = ws + OFF_XT;
    float* ept   = ws + OFF_EPT;
    float* xproj = ws + OFF_XPROJ;
    float* iproj = ws + OFF_IPROJ;
    int blk = blockIdx.x, tid = threadIdx.x;
    if (blk < 256) {
        int k = blk, s = tid;
        double a = 0.0;
        for (int e = 0; e < 256; ++e)
            a += (double)Wae[(size_t)k * 256 + e] * (double)xt[(size_t)e * 512 + s];
        ept[(size_t)k * 512 + s] = (float)((double)ba[k] + a);
    } else if (blk < 256 + 1024) {
        int idx = blk - 256;
        int s = idx >> 1;
        int r = (idx & 1) * 512 + tid;
        double a = 0.0;
        for (int e = 0; e < 256; ++e)
            a += (double)x[(size_t)s * 256 + e] * (double)wiht[(size_t)e * 1024 + r];
        xproj[(size_t)s * 1024 + r] = (float)a;
    } else {
        int r = (blk - 1280) * 512 + tid;
        double a = 0.0;
        for (int e = 0; e < 256; ++e)
            a += (double)idec[e] * (double)wiht[(size_t)e * 1024 + r];
        iproj[r] = (float)a;
    }
}

// ---------------- persistent decode: 256 WGs = 16 groups x 16 slices ----------------
// group g = blockIdx & 15 -> all 16 WGs of a group share blockIdx mod 8 (same XCD
// under round-robin dispatch; perf heuristic only, correctness placement-free)
__global__ __launch_bounds__(512, 2) void k_decode(
    const float* __restrict__ gmb, const float* __restrict__ vvec,
    const float* __restrict__ Whh, const float* __restrict__ Wad,
    float* __restrict__ ws, float* __restrict__ out)
{
    extern __shared__ char smem[];
    float*  pb   = (float*)(smem + L_UNION);
    double* pp3  = (double*)(smem + L_UNION);
    double* pf   = (double*)(smem + L_UNION);
    double* vLd  = (double*)(smem + L_VLD);
    float*  es_l = (float*)(smem + L_ES);
    float*  wa_l = (float*)(smem + L_WAD);
    float*  hf   = (float*)(smem + L_HF);
    float*  hwf  = (float*)(smem + L_HWF);
    float*  xpro = (float*)(smem + L_XPRO);
    float*  mask = (float*)(smem + L_MASK);
    float*  c_l  = (float*)(smem + L_CL);
    float*  bias_l = (float*)(smem + L_BIAS);
    int*    selA = (int*)(smem + L_SEL);

    const int tid = threadIdx.x;
    const int g = blockIdx.x & 15;      // sample group (same XCD class)
    const int q = blockIdx.x >> 4;      // slice

    const float* eptG   = ws + OFF_EPT;
    const float* xprojG = ws + OFF_XPROJ;
    const float* biasG  = ws + OFF_BIAS;
    const float* iprojG = ws + OFF_IPROJ;
    float* hex  = ws + OFF_HEX  + (size_t)g * 2048;
    float* waex = ws + OFF_WAEX + (size_t)g * 2048;
    float* lex  = ws + OFF_LEX  + (size_t)g * 4096;
    int*   barI = (int*)(ws + OFF_BAR) + (size_t)g * 1536;

    // ---- one-time LDS fills ----
    for (int i = tid; i < 8192; i += 512) {
        int k = i >> 5, ss = i & 31;
        es_l[i] = eptG[(size_t)k * 512 + q * 32 + ss];
    }
    for (int i = tid; i < 4096; i += 512) {
        int k = i >> 4, rl = i & 15;
        wa_l[i] = Wad[(size_t)(q * 16 + rl) * 256 + k];
    }
    for (int i = tid; i < 256; i += 512) vLd[i] = (double)vvec[i];
    if (tid < 64) bias_l[tid] = biasG[((tid >> 4) << 8) + q * 16 + (tid & 15)];
    for (int i = tid; i < 256; i += 512) mask[i] = 0.f;
    for (int i = tid; i < 128; i += 512) c_l[i] = 0.f;
    for (int i = tid; i < 2080; i += 512) { hf[i] = 0.f; hwf[i] = 0.f; }
    {
        int sl = tid >> 6, rl = tid & 63;
        int rg = ((rl >> 4) << 8) + q * 16 + (rl & 15);
        xpro[sl * 64 + rl] = iprojG[rg];
    }

    // ---- W_hh slice into registers ----
    const int w = tid >> 6, lane = tid & 63;
    const int rl1 = lane;
    const int rg1 = ((rl1 >> 4) << 8) + q * 16 + (rl1 & 15);
    const int kbase = w * 32;
    float wreg[32];
    {
        const float4* wrow = (const float4*)(Whh + (size_t)rg1 * 256 + kbase);
        #pragma unroll
        for (int j = 0; j < 8; ++j) {
            float4 v4 = wrow[j];
            wreg[4 * j + 0] = v4.x; wreg[4 * j + 1] = v4.y;
            wreg[4 * j + 2] = v4.z; wreg[4 * j + 3] = v4.w;
        }
    }
    __syncthreads();

    float lps = 0.f;

    for (int t = 0; t < SN; ++t) {
        int* barp = barI + t * 3;

        // ---- gumbel prefetch for this wave's sample (nontemporal; hidden latency)
        float gv8[8];
        {
            const float* growW = gmb + (size_t)t * (BN * SN) + (size_t)(g * 8 + w) * SN;
            #pragma unroll
            for (int j = 0; j < 8; ++j)
                gv8[j] = __builtin_nontemporal_load(growW + lane + 64 * j);
        }

        // ---- phase 1: gate partials ----
        #pragma unroll
        for (int sl = 0; sl < 8; ++sl) {
            float a = 0.f;
            #pragma unroll
            for (int g4 = 0; g4 < 8; ++g4) {
                float4 h4 = *(const float4*)(hf + sl * 260 + kbase + 4 * g4);
                a = fmaf(wreg[4 * g4 + 0], h4.x, a);
                a = fmaf(wreg[4 * g4 + 1], h4.y, a);
                a = fmaf(wreg[4 * g4 + 2], h4.z, a);
                a = fmaf(wreg[4 * g4 + 3], h4.w, a);
            }
            pb[w * 576 + rl1 * 9 + sl] = a;
        }
        __syncthreads();

        // ---- phase 2: reduce gates + LSTM; publish h slice; arrive B1 ----
        if (tid < 128) {
            int jl = tid >> 3, sl = tid & 7;
            float gv[4];
            #pragma unroll
            for (int gate = 0; gate < 4; ++gate) {
                int rl = gate * 16 + jl;
                float p0 = pb[0 * 576 + rl * 9 + sl], p1 = pb[1 * 576 + rl * 9 + sl];
                float p2 = pb[2 * 576 + rl * 9 + sl], p3 = pb[3 * 576 + rl * 9 + sl];
                float p4 = pb[4 * 576 + rl * 9 + sl], p5 = pb[5 * 576 + rl * 9 + sl];
                float p6 = pb[6 * 576 + rl * 9 + sl], p7 = pb[7 * 576 + rl * 9 + sl];
                float s8 = ((p0 + p1) + (p2 + p3)) + ((p4 + p5) + (p6 + p7));
                gv[gate] = bias_l[rl] + xpro[sl * 64 + rl] + s8;
            }
            float si = 1.0f / (1.0f + expf(-gv[0]));
            float sf = 1.0f / (1.0f + expf(-gv[1]));
            float so = 1.0f / (1.0f + expf(-gv[3]));
            float cf = sf * c_l[jl * 8 + sl] + si * tanhf(gv[2]);
            float hn = so * tanhf(cf);
            c_l[jl * 8 + sl] = cf;
            st_agent(&hex[sl * 256 + q * 16 + jl], hn);
            wave_arrive(barp + 0, tid);
        }
        wave_poll(barp + 0, 2 * NSLICE);
        {   // gather full h (agent loads, bypass stale L2)
            int idx = tid * 4; int sl = idx >> 8, j = idx & 255;
            float f0 = ld_agent(hex + sl * 256 + j + 0);
            float f1 = ld_agent(hex + sl * 256 + j + 1);
            float f2 = ld_agent(hex + sl * 256 + j + 2);
            float f3 = ld_agent(hex + sl * 256 + j + 3);
            float4 v4 = make_float4(f0, f1, f2, f3);
            *(float4*)(hf + sl * 260 + j) = v4;
        }
        __syncthreads();

        // ---- phase 3: hWa partials ----
        {
            int kc = tid >> 4, rl = tid & 15;
            float w3[8];
            #pragma unroll
            for (int kk = 0; kk < 8; ++kk) w3[kk] = wa_l[(kc * 8 + kk) * 16 + rl];
            #pragma unroll
            for (int sl = 0; sl < 8; ++sl) {
                double a = 0.0;
                #pragma unroll
                for (int kk = 0; kk < 8; ++kk)
                    a += (double)w3[kk] * (double)hf[sl * 260 + kc * 8 + kk];
                pp3[kc * 144 + rl * 9 + sl] = a;
            }
        }
        __syncthreads();
        if (tid < 128) {
            int rl = tid >> 3, sl = tid & 7;
            double s = 0.0;
            for (int kc = 0; kc < 32; ++kc) s += pp3[kc * 144 + rl * 9 + sl];
            st_agent(&waex[sl * 256 + q * 16 + rl], (float)s);
            wave_arrive(barp + 1, tid);
        }
        wave_poll(barp + 1, 2 * NSLICE);
        {   // gather full hWa
            int idx = tid * 4; int sl = idx >> 8, j = idx & 255;
            float f0 = ld_agent(waex + sl * 256 + j + 0);
            float f1 = ld_agent(waex + sl * 256 + j + 1);
            float f2 = ld_agent(waex + sl * 256 + j + 2);
            float f3 = ld_agent(waex + sl * 256 + j + 3);
            float4 v4 = make_float4(f0, f1, f2, f3);
            *(float4*)(hwf + sl * 260 + j) = v4;
        }
        __syncthreads();

        // ---- phase 4: attention partials ----
        {
            int kc4 = tid >> 5, ss = tid & 31;
            float ev[16]; double vd[16];
            #pragma unroll
            for (int kk = 0; kk < 16; ++kk) {
                ev[kk] = es_l[(kc4 * 16 + kk) * 32 + ss];
                vd[kk] = vLd[kc4 * 16 + kk];
            }
            #pragma unroll
            for (int sl = 0; sl < 8; ++sl) {
                float hw[16];
                #pragma unroll
                for (int j = 0; j < 4; ++j) {
                    float4 h4 = *(const float4*)(hwf + sl * 260 + kc4 * 16 + 4 * j);
                    hw[4 * j + 0] = h4.x; hw[4 * j + 1] = h4.y;
                    hw[4 * j + 2] = h4.z; hw[4 * j + 3] = h4.w;
                }
                double a = 0.0;
                #pragma unroll
                for (int kk = 0; kk < 16; ++kk) {
                    float tt = tanh_fast(ev[kk] + hw[kk]);
                    a += vd[kk] * (double)tt;
                }
                pf[kc4 * 288 + ss * 9 + sl] = a;
            }
        }
        __syncthreads();
        if (tid < 256) {   // reduce + logits + mask; publish; arrive B3
            int ss = tid >> 3, sl = tid & 7;
            double u = 0.0;
            for (int kc = 0; kc < 16; ++kc) u += pf[kc * 288 + ss * 9 + sl];
            float lg = (float)(10.0 * tanh(u));
            st_agent(&lex[sl * 512 + q * 32 + ss], lg + mask[ss * 8 + sl]);
            wave_arrive(barp + 2, tid);
        }
        wave_poll(barp + 2, 4 * NSLICE);

        // ---- phase 5: exact flat log-softmax + Gumbel argmax; wave w <-> sample w ----
        {
            int sl = w;
            const float* lrow = lex + sl * 512;
            float lv[8];
            float M = -INFINITY;
            #pragma unroll
            for (int j = 0; j < 8; ++j) { lv[j] = ld_agent(lrow + lane + 64 * j); M = fmaxf(M, lv[j]); }
            #pragma unroll
            for (int off = 32; off >= 1; off >>= 1) M = fmaxf(M, __shfl_xor(M, off, 64));
            float se = 0.f;
            #pragma unroll
            for (int j = 0; j < 8; ++j) se += expf(lv[j] - M);
            #pragma unroll
            for (int off = 32; off >= 1; off >>= 1) se += __shfl_xor(se, off, 64);
            float logS = logf(se);
            float best = -INFINITY; int bidx = 0x7fffffff; float blp = 0.f;
            #pragma unroll
            for (int j = 0; j < 8; ++j) {
                int s = lane + 64 * j;
                float lp = (lv[j] - M) - logS;
                float cd = lp + gv8[j];
                if (cd > best || (cd == best && s < bidx)) { best = cd; bidx = s; blp = lp; }
            }
            #pragma unroll
            for (int off = 32; off >= 1; off >>= 1) {
                float ob = __shfl_xor(best, off, 64);
                int   oi = __shfl_xor(bidx, off, 64);
                float ol = __shfl_xor(blp, off, 64);
                if (ob > best || (ob == best && oi < bidx)) { best = ob; bidx = oi; blp = ol; }
            }
            lps += blp;
            if (lane == 0) {
                selA[sl] = bidx;
                if (q == 0) out[(size_t)(g * 8 + sl) * SN + t] = (float)bidx;
            }
        }
        __syncthreads();
        // ---- mask update + next-step xpro gather ----
        if (tid < 256) {
            int ss = tid >> 3, sl = tid & 7;
            if (selA[sl] == q * 32 + ss) mask[ss * 8 + sl] = -INFINITY;
        }
        {
            int sl = tid >> 6, rl = tid & 63;
            int rg = ((rl >> 4) << 8) + q * 16 + (rl & 15);
            xpro[sl * 64 + rl] = xprojG[(size_t)selA[sl] * 1024 + rg];
        }
        __syncthreads();
    }
    if (q == 0 && lane == 0) out[(size_t)BN * SN + g * 8 + w] = lps;
}

extern "C" void kernel_launch(void* const* d_in, const int* in_sizes, int n_in,
                              void* d_out, int out_size, void* d_ws, size_t ws_size,
                              hipStream_t stream)
{
    const float* x    = (const float*)d_in[0];
    const float* gmb  = (const float*)d_in[1];
    const float* Wih  = (const float*)d_in[2];
    const float* Whh  = (const float*)d_in[3];
    const float* bih  = (const float*)d_in[4];
    const float* bhh  = (const float*)d_in[5];
    const float* Wad  = (const float*)d_in[6];
    const float* Wae  = (const float*)d_in[7];
    const float* ba   = (const float*)d_in[8];
    const float* vvec = (const float*)d_in[9];
    const float* idec = (const float*)d_in[10];
    float* ws = (float*)d_ws;
    float* out = (float*)d_out;

    hipFuncSetAttribute(reinterpret_cast<const void*>(k_decode),
                        hipFuncAttributeMaxDynamicSharedMemorySize, SMEM_TOTAL);

    hipLaunchKernelGGL(k_init_transpose, dim3(1636), dim3(256), 0, stream,
                       Wih, bih, bhh, x, ws);
    hipLaunchKernelGGL(k_init_proj, dim3(1282), dim3(512), 0, stream,
                       x, Wae, ba, idec, ws);
    hipLaunchKernelGGL(k_decode, dim3(256), dim3(512), SMEM_TOTAL, stream,
                       gmb, vvec, Whh, Wad, ws, out);
}

// Round 4
// 11114.014 us; speedup vs baseline: 2.9507x; 1.2559x over previous
//
#include <hip/hip_runtime.h>
#include <math.h>

#define SN 512
#define BN 128
#define HN 256
#define G4 1024
#define NSLICE 16   // slices per sample-group
#define NGRP   16   // sample groups

// ---- workspace layout (float offsets) ----
#define OFF_EPT    ((size_t)0)                       // enc_proj^T [256][512]
#define OFF_XPROJ  ((size_t)131072)                  // X_proj [512][1024]
#define OFF_WIHT   ((size_t)655360)                  // W_ih^T [256][1024]
#define OFF_XT     ((size_t)917504)                  // x^T [256][512]
#define OFF_BIAS   ((size_t)1048576)                 // b_ih+b_hh [1024]
#define OFF_IPROJ  ((size_t)1049600)                 // W_ih@init_dec [1024]
#define OFF_HEX    ((size_t)1050624)                 // h exchange [16][8*256]
#define OFF_WAEX   ((size_t)1083392)                 // hWa exchange [16][8*256]
#define OFF_LEX    ((size_t)1116160)                 // logits exchange [16][8*512]
#define OFF_BAR    ((size_t)1181696)                 // barriers [16][512][6][16] ints
#define BAR_INTS   (16*512*6*16)                     // 786432 (64B per counter)

// ---- dynamic LDS layout (byte offsets) ----
#define L_UNION 0        // 36864 B: pb f32[8][64][9] / pp3 f64[32][16][9] / pf f64[16][32][9]
#define L_VLD   36864    // 2048 B: v as f64 [256]
#define L_ES    38912    // 32768 B: ept slice [256][32]
#define L_WAD   71680    // 16384 B: Wa_dec slice [256][16]
#define L_HF    88064    // 8320 B: h full [8][260]
#define L_HWF   96384    // 8320 B: hWa full [8][260]
#define L_XPRO  104704   // 2048 B: x-proj rows [8][64]
#define L_MASK  106752   // 1024 B: mask chunk [32][8]
#define L_CL    107776   // 512 B: c chunk [16][8]
#define L_BIAS  108288   // 256 B: bias rows [64]
#define L_SEL   108544   // 32 B: selected idx [8]
#define SMEM_TOTAL 108576

__device__ __forceinline__ float tanh_fast(float x) {
    float a = fabsf(x);
    float e = __builtin_amdgcn_exp2f(a * -2.8853900817779268f);
    float r = (1.0f - e) * __builtin_amdgcn_rcpf(1.0f + e);
    return copysignf(r, x);
}

// ---- coherent-point (MALL) access helpers: bypass L1/L2 via sc0 sc1 ----
__device__ __forceinline__ void stg_sc1(float* p, float v) {
    asm volatile("global_store_dword %0, %1, off sc0 sc1" :: "v"(p), "v"(v) : "memory");
}
__device__ __forceinline__ void waitvm() {
    asm volatile("s_waitcnt vmcnt(0)" ::: "memory");
}
__device__ __forceinline__ float2 ldg_sc2w(const float* p) {   // load + wait
    float2 r;
    asm volatile("global_load_dwordx2 %0, %1, off sc0 sc1\n\ts_waitcnt vmcnt(0)"
                 : "=v"(r) : "v"(p) : "memory");
    return r;
}
__device__ __forceinline__ int ldg_sciw(const int* p) {
    int r;
    asm volatile("global_load_dword %0, %1, off sc0 sc1\n\ts_waitcnt vmcnt(0)"
                 : "=v"(r) : "v"(p) : "memory");
    return r;
}
__device__ __forceinline__ void poll_ge(int* cnt, int target) {
    while (ldg_sciw(cnt) < target) __builtin_amdgcn_s_sleep(1);
}
__device__ __forceinline__ void bar_add(int* cnt) {
    __hip_atomic_fetch_add(cnt, 1, __ATOMIC_RELAXED, __HIP_MEMORY_SCOPE_AGENT);
}

// ---------------- init kernel 1: transposes + bias + barrier zero ----------------
__global__ __launch_bounds__(256) void k_init_transpose(
    const float* __restrict__ Wih, const float* __restrict__ bih,
    const float* __restrict__ bhh, const float* __restrict__ x,
    float* __restrict__ ws)
{
    float* wiht = ws + OFF_WIHT;
    float* xt   = ws + OFF_XT;
    float* bias = ws + OFF_BIAS;
    int*   bar  = (int*)(ws + OFF_BAR);
    int i = blockIdx.x * 256 + threadIdx.x;
    if (i < 262144) {                        // W_ih^T [e][r]
        int e = i >> 10, r = i & 1023;
        wiht[i] = Wih[(size_t)r * 256 + e];
    } else if (i < 393216) {                 // x^T [e][s]
        int j = i - 262144; int e = j >> 9, s = j & 511;
        xt[j] = x[(size_t)s * 256 + e];
    } else if (i < 394240) {                 // bias
        int j = i - 393216;
        bias[j] = bih[j] + bhh[j];
    } else if (i < 394240 + BAR_INTS) {      // zero barriers
        bar[i - 394240] = 0;
    }
}

// ---------------- init kernel 2: projections (double-accum) ----------------
__global__ __launch_bounds__(512) void k_init_proj(
    const float* __restrict__ x, const float* __restrict__ Wae,
    const float* __restrict__ ba, const float* __restrict__ idec,
    float* __restrict__ ws)
{
    const float* wiht = ws + OFF_WIHT;
    const float* xt   = ws + OFF_XT;
    float* ept   = ws + OFF_EPT;
    float* xproj = ws + OFF_XPROJ;
    float* iproj = ws + OFF_IPROJ;
    int blk = blockIdx.x, tid = threadIdx.x;
    if (blk < 256) {
        int k = blk, s = tid;
        double a = 0.0;
        for (int e = 0; e < 256; ++e)
            a += (double)Wae[(size_t)k * 256 + e] * (double)xt[(size_t)e * 512 + s];
        ept[(size_t)k * 512 + s] = (float)((double)ba[k] + a);
    } else if (blk < 256 + 1024) {
        int idx = blk - 256;
        int s = idx >> 1;
        int r = (idx & 1) * 512 + tid;
        double a = 0.0;
        for (int e = 0; e < 256; ++e)
            a += (double)x[(size_t)s * 256 + e] * (double)wiht[(size_t)e * 1024 + r];
        xproj[(size_t)s * 1024 + r] = (float)a;
    } else {
        int r = (blk - 1280) * 512 + tid;
        double a = 0.0;
        for (int e = 0; e < 256; ++e)
            a += (double)idec[e] * (double)wiht[(size_t)e * 1024 + r];
        iproj[r] = (float)a;
    }
}

// ---------------- persistent decode: 256 WGs = 16 groups x 16 slices ----------------
// Samples split into set A (sl 0-3, waves 0-3) and set B (sl 4-7, waves 4-7);
// set B's compute overlaps set A's barrier latency and vice versa.
__global__ __launch_bounds__(512, 2) void k_decode(
    const float* __restrict__ gmb, const float* __restrict__ vvec,
    const float* __restrict__ Whh, const float* __restrict__ Wad,
    float* __restrict__ ws, float* __restrict__ out)
{
    extern __shared__ char smem[];
    float*  pb   = (float*)(smem + L_UNION);
    double* pp3  = (double*)(smem + L_UNION);
    double* pf   = (double*)(smem + L_UNION);
    double* vLd  = (double*)(smem + L_VLD);
    float*  es_l = (float*)(smem + L_ES);
    float*  wa_l = (float*)(smem + L_WAD);
    float*  hf   = (float*)(smem + L_HF);
    float*  hwf  = (float*)(smem + L_HWF);
    float*  xpro = (float*)(smem + L_XPRO);
    float*  mask = (float*)(smem + L_MASK);
    float*  c_l  = (float*)(smem + L_CL);
    float*  bias_l = (float*)(smem + L_BIAS);
    int*    selA = (int*)(smem + L_SEL);

    const int tid = threadIdx.x;
    const int g = blockIdx.x & 15;      // sample group (shares XCD class)
    const int q = blockIdx.x >> 4;      // slice

    const float* eptG   = ws + OFF_EPT;
    const float* xprojG = ws + OFF_XPROJ;
    const float* biasG  = ws + OFF_BIAS;
    const float* iprojG = ws + OFF_IPROJ;
    float* hex  = ws + OFF_HEX  + (size_t)g * 2048;
    float* waex = ws + OFF_WAEX + (size_t)g * 2048;
    float* lex  = ws + OFF_LEX  + (size_t)g * 4096;
    int*   barI = (int*)(ws + OFF_BAR) + (size_t)g * 49152;

    // ---- one-time LDS fills ----
    for (int i = tid; i < 8192; i += 512) {
        int k = i >> 5, ss = i & 31;
        es_l[i] = eptG[(size_t)k * 512 + q * 32 + ss];
    }
    for (int i = tid; i < 4096; i += 512) {
        int k = i >> 4, rl = i & 15;
        wa_l[i] = Wad[(size_t)(q * 16 + rl) * 256 + k];
    }
    for (int i = tid; i < 256; i += 512) vLd[i] = (double)vvec[i];
    if (tid < 64) bias_l[tid] = biasG[((tid >> 4) << 8) + q * 16 + (tid & 15)];
    for (int i = tid; i < 256; i += 512) mask[i] = 0.f;
    for (int i = tid; i < 128; i += 512) c_l[i] = 0.f;
    for (int i = tid; i < 2080; i += 512) { hf[i] = 0.f; hwf[i] = 0.f; }
    {
        int sl = tid >> 6, rl = tid & 63;
        int rg = ((rl >> 4) << 8) + q * 16 + (rl & 15);
        xpro[sl * 64 + rl] = iprojG[rg];
    }

    // ---- W_hh slice into registers ----
    const int w = tid >> 6, lane = tid & 63;
    const int rg1 = ((lane >> 4) << 8) + q * 16 + (lane & 15);
    const int kbase = w * 32;
    float wreg[32];
    {
        const float4* wrow = (const float4*)(Whh + (size_t)rg1 * 256 + kbase);
        #pragma unroll
        for (int j = 0; j < 8; ++j) {
            float4 v4 = wrow[j];
            wreg[4 * j + 0] = v4.x; wreg[4 * j + 1] = v4.y;
            wreg[4 * j + 2] = v4.z; wreg[4 * j + 3] = v4.w;
        }
    }
    __syncthreads();

    float lps = 0.f;

    for (int t = 0; t < SN; ++t) {
        int* barp = barI + t * 96;   // 6 counters x 16-int stride

        // ---- gumbel prefetch (wave w <-> sample w) ----
        float gv8[8];
        {
            const float* growW = gmb + (size_t)t * (BN * SN) + (size_t)(g * 8 + w) * SN;
            #pragma unroll
            for (int j = 0; j < 8; ++j)
                gv8[j] = __builtin_nontemporal_load(growW + lane + 64 * j);
        }

        // ================= P1(A): gate partials, sl 0-3 =================
        #pragma unroll
        for (int slin = 0; slin < 4; ++slin) {
            int sl = slin;
            float a0 = 0.f, a1 = 0.f, a2 = 0.f, a3 = 0.f;
            #pragma unroll
            for (int g4 = 0; g4 < 8; ++g4) {
                float4 h4 = *(const float4*)(hf + sl * 260 + kbase + 4 * g4);
                a0 = fmaf(wreg[4 * g4 + 0], h4.x, a0);
                a1 = fmaf(wreg[4 * g4 + 1], h4.y, a1);
                a2 = fmaf(wreg[4 * g4 + 2], h4.z, a2);
                a3 = fmaf(wreg[4 * g4 + 3], h4.w, a3);
            }
            pb[w * 576 + lane * 9 + sl] = ((a0 + a1) + (a2 + a3));
        }
        __syncthreads();

        // ---- P2(A): LSTM cell by wave 0; publish h(A); arrive B1A ----
        if (w == 0) {
            int jl = lane & 15, slin = lane >> 4;
            int sl = slin;
            float gvv[4];
            #pragma unroll
            for (int gate = 0; gate < 4; ++gate) {
                int rl = gate * 16 + jl;
                float p0 = pb[0 * 576 + rl * 9 + sl], p1 = pb[1 * 576 + rl * 9 + sl];
                float p2 = pb[2 * 576 + rl * 9 + sl], p3 = pb[3 * 576 + rl * 9 + sl];
                float p4 = pb[4 * 576 + rl * 9 + sl], p5 = pb[5 * 576 + rl * 9 + sl];
                float p6 = pb[6 * 576 + rl * 9 + sl], p7 = pb[7 * 576 + rl * 9 + sl];
                float s8 = ((p0 + p1) + (p2 + p3)) + ((p4 + p5) + (p6 + p7));
                gvv[gate] = bias_l[rl] + xpro[sl * 64 + rl] + s8;
            }
            float si = 1.0f / (1.0f + expf(-gvv[0]));
            float sf = 1.0f / (1.0f + expf(-gvv[1]));
            float so = 1.0f / (1.0f + expf(-gvv[3]));
            float cf = sf * c_l[jl * 8 + sl] + si * tanhf(gvv[2]);
            float hn = so * tanhf(cf);
            c_l[jl * 8 + sl] = cf;
            stg_sc1(&hex[sl * 256 + q * 16 + jl], hn);
            waitvm();
            if (lane == 0) bar_add(barp + 0 * 16);
        }

        // ================= P1(B): gate partials, sl 4-7 (overlaps B1A) ==
        #pragma unroll
        for (int slin = 0; slin < 4; ++slin) {
            int sl = 4 + slin;
            float a0 = 0.f, a1 = 0.f, a2 = 0.f, a3 = 0.f;
            #pragma unroll
            for (int g4 = 0; g4 < 8; ++g4) {
                float4 h4 = *(const float4*)(hf + sl * 260 + kbase + 4 * g4);
                a0 = fmaf(wreg[4 * g4 + 0], h4.x, a0);
                a1 = fmaf(wreg[4 * g4 + 1], h4.y, a1);
                a2 = fmaf(wreg[4 * g4 + 2], h4.z, a2);
                a3 = fmaf(wreg[4 * g4 + 3], h4.w, a3);
            }
            pb[w * 576 + lane * 9 + sl] = ((a0 + a1) + (a2 + a3));
        }
        __syncthreads();

        // ---- P2(B): LSTM cell by wave 1; publish h(B); arrive B1B ----
        if (w == 1) {
            int jl = lane & 15, slin = lane >> 4;
            int sl = 4 + slin;
            float gvv[4];
            #pragma unroll
            for (int gate = 0; gate < 4; ++gate) {
                int rl = gate * 16 + jl;
                float p0 = pb[0 * 576 + rl * 9 + sl], p1 = pb[1 * 576 + rl * 9 + sl];
                float p2 = pb[2 * 576 + rl * 9 + sl], p3 = pb[3 * 576 + rl * 9 + sl];
                float p4 = pb[4 * 576 + rl * 9 + sl], p5 = pb[5 * 576 + rl * 9 + sl];
                float p6 = pb[6 * 576 + rl * 9 + sl], p7 = pb[7 * 576 + rl * 9 + sl];
                float s8 = ((p0 + p1) + (p2 + p3)) + ((p4 + p5) + (p6 + p7));
                gvv[gate] = bias_l[rl] + xpro[sl * 64 + rl] + s8;
            }
            float si = 1.0f / (1.0f + expf(-gvv[0]));
            float sf = 1.0f / (1.0f + expf(-gvv[1]));
            float so = 1.0f / (1.0f + expf(-gvv[3]));
            float cf = sf * c_l[jl * 8 + sl] + si * tanhf(gvv[2]);
            float hn = so * tanhf(cf);
            c_l[jl * 8 + sl] = cf;
            stg_sc1(&hex[sl * 256 + q * 16 + jl], hn);
            waitvm();
            if (lane == 0) bar_add(barp + 1 * 16);
        }

        // ---- B1A poll + gather h(A) ----
        poll_ge(barp + 0 * 16, NSLICE);
        {
            int off = 2 * tid;                 // [0,1024)
            int sl = off >> 8, j = off & 255;
            float2 v2 = ldg_sc2w(hex + off);
            *(float2*)(hf + sl * 260 + j) = v2;
        }
        __syncthreads();

        // ================= P3(A): hWa partials, sl 0-3 =================
        {
            int kc = tid >> 4, rl = tid & 15;
            float w3[8];
            #pragma unroll
            for (int kk = 0; kk < 8; ++kk) w3[kk] = wa_l[(kc * 8 + kk) * 16 + rl];
            #pragma unroll
            for (int sl = 0; sl < 4; ++sl) {
                double a = 0.0;
                #pragma unroll
                for (int kk = 0; kk < 8; ++kk)
                    a += (double)w3[kk] * (double)hf[sl * 260 + kc * 8 + kk];
                pp3[kc * 144 + rl * 9 + sl] = a;
            }
        }
        __syncthreads();
        // ---- P3(A) reduce by wave 2; publish hWa(A); arrive B2A ----
        if (w == 2) {
            int rl = lane & 15, slin = lane >> 4;
            int sl = slin;
            double s = 0.0;
            for (int kc = 0; kc < 32; ++kc) s += pp3[kc * 144 + rl * 9 + sl];
            stg_sc1(&waex[sl * 256 + q * 16 + rl], (float)s);
            waitvm();
            if (lane == 0) bar_add(barp + 2 * 16);
        }

        // ---- B1B poll + gather h(B) (overlaps B2A) ----
        poll_ge(barp + 1 * 16, NSLICE);
        {
            int off = 1024 + 2 * tid;
            int sl = off >> 8, j = off & 255;
            float2 v2 = ldg_sc2w(hex + off);
            *(float2*)(hf + sl * 260 + j) = v2;
        }
        __syncthreads();

        // ================= P3(B): hWa partials, sl 4-7 =================
        {
            int kc = tid >> 4, rl = tid & 15;
            float w3[8];
            #pragma unroll
            for (int kk = 0; kk < 8; ++kk) w3[kk] = wa_l[(kc * 8 + kk) * 16 + rl];
            #pragma unroll
            for (int slin = 0; slin < 4; ++slin) {
                int sl = 4 + slin;
                double a = 0.0;
                #pragma unroll
                for (int kk = 0; kk < 8; ++kk)
                    a += (double)w3[kk] * (double)hf[sl * 260 + kc * 8 + kk];
                pp3[kc * 144 + rl * 9 + sl] = a;
            }
        }
        __syncthreads();
        // ---- P3(B) reduce by wave 3; publish hWa(B); arrive B2B ----
        if (w == 3) {
            int rl = lane & 15, slin = lane >> 4;
            int sl = 4 + slin;
            double s = 0.0;
            for (int kc = 0; kc < 32; ++kc) s += pp3[kc * 144 + rl * 9 + sl];
            stg_sc1(&waex[sl * 256 + q * 16 + rl], (float)s);
            waitvm();
            if (lane == 0) bar_add(barp + 3 * 16);
        }

        // ---- B2A poll + gather hWa(A) ----
        poll_ge(barp + 2 * 16, NSLICE);
        {
            int off = 2 * tid;
            int sl = off >> 8, j = off & 255;
            float2 v2 = ldg_sc2w(waex + off);
            *(float2*)(hwf + sl * 260 + j) = v2;
        }
        __syncthreads();

        // ================= P4(A): attention partials, sl 0-3 ============
        {
            int kc4 = tid >> 5, ss = tid & 31;
            float ev[16]; double vd[16];
            #pragma unroll
            for (int kk = 0; kk < 16; ++kk) {
                ev[kk] = es_l[(kc4 * 16 + kk) * 32 + ss];
                vd[kk] = vLd[kc4 * 16 + kk];
            }
            #pragma unroll
            for (int sl = 0; sl < 4; ++sl) {
                float hw[16];
                #pragma unroll
                for (int j = 0; j < 4; ++j) {
                    float4 h4 = *(const float4*)(hwf + sl * 260 + kc4 * 16 + 4 * j);
                    hw[4 * j + 0] = h4.x; hw[4 * j + 1] = h4.y;
                    hw[4 * j + 2] = h4.z; hw[4 * j + 3] = h4.w;
                }
                double a = 0.0;
                #pragma unroll
                for (int kk = 0; kk < 16; ++kk) {
                    float tt = tanh_fast(ev[kk] + hw[kk]);
                    a += vd[kk] * (double)tt;
                }
                pf[kc4 * 288 + ss * 9 + sl] = a;
            }
        }
        __syncthreads();
        // ---- P4(A) reduce by waves 0-1; publish logits(A); arrive B3A ----
        if (tid < 128) {
            int ss = tid & 31, slin = tid >> 5;
            int sl = slin;
            double u = 0.0;
            for (int kc = 0; kc < 16; ++kc) u += pf[kc * 288 + ss * 9 + sl];
            float lg = (float)(10.0 * tanh(u));
            stg_sc1(&lex[sl * 512 + q * 32 + ss], lg + mask[ss * 8 + sl]);
            waitvm();
            if (lane == 0) bar_add(barp + 4 * 16);
        }

        // ---- B2B poll + gather hWa(B) (overlaps B3A) ----
        poll_ge(barp + 3 * 16, NSLICE);
        {
            int off = 1024 + 2 * tid;
            int sl = off >> 8, j = off & 255;
            float2 v2 = ldg_sc2w(waex + off);
            *(float2*)(hwf + sl * 260 + j) = v2;
        }
        __syncthreads();

        // ================= P4(B): attention partials, sl 4-7 ============
        {
            int kc4 = tid >> 5, ss = tid & 31;
            float ev[16]; double vd[16];
            #pragma unroll
            for (int kk = 0; kk < 16; ++kk) {
                ev[kk] = es_l[(kc4 * 16 + kk) * 32 + ss];
                vd[kk] = vLd[kc4 * 16 + kk];
            }
            #pragma unroll
            for (int slin = 0; slin < 4; ++slin) {
                int sl = 4 + slin;
                float hw[16];
                #pragma unroll
                for (int j = 0; j < 4; ++j) {
                    float4 h4 = *(const float4*)(hwf + sl * 260 + kc4 * 16 + 4 * j);
                    hw[4 * j + 0] = h4.x; hw[4 * j + 1] = h4.y;
                    hw[4 * j + 2] = h4.z; hw[4 * j + 3] = h4.w;
                }
                double a = 0.0;
                #pragma unroll
                for (int kk = 0; kk < 16; ++kk) {
                    float tt = tanh_fast(ev[kk] + hw[kk]);
                    a += vd[kk] * (double)tt;
                }
                pf[kc4 * 288 + ss * 9 + sl] = a;
            }
        }
        __syncthreads();
        // ---- P4(B) reduce by waves 0-1; publish logits(B); arrive B3B ----
        if (tid < 128) {
            int ss = tid & 31, slin = tid >> 5;
            int sl = 4 + slin;
            double u = 0.0;
            for (int kc = 0; kc < 16; ++kc) u += pf[kc * 288 + ss * 9 + sl];
            float lg = (float)(10.0 * tanh(u));
            stg_sc1(&lex[sl * 512 + q * 32 + ss], lg + mask[ss * 8 + sl]);
            waitvm();
            if (lane == 0) bar_add(barp + 5 * 16);
        }

        // ================= P5: softmax+argmax; wave w <-> sample w ======
        {
            poll_ge(barp + (w < 4 ? 4 : 5) * 16, 2 * NSLICE);
            const float* lrow = lex + w * 512;
            float lv[8];
            #pragma unroll
            for (int j = 0; j < 8; ++j) {
                asm volatile("global_load_dword %0, %1, off sc0 sc1"
                             : "=v"(lv[j]) : "v"(lrow + lane + 64 * j) : "memory");
            }
            waitvm();
            float M = -INFINITY;
            #pragma unroll
            for (int j = 0; j < 8; ++j) M = fmaxf(M, lv[j]);
            #pragma unroll
            for (int off = 32; off >= 1; off >>= 1) M = fmaxf(M, __shfl_xor(M, off, 64));
            float se = 0.f;
            #pragma unroll
            for (int j = 0; j < 8; ++j) se += expf(lv[j] - M);
            #pragma unroll
            for (int off = 32; off >= 1; off >>= 1) se += __shfl_xor(se, off, 64);
            float logS = logf(se);
            float best = -INFINITY; int bidx = 0x7fffffff; float blp = 0.f;
            #pragma unroll
            for (int j = 0; j < 8; ++j) {
                int s = lane + 64 * j;
                float lp = (lv[j] - M) - logS;
                float cd = lp + gv8[j];
                if (cd > best || (cd == best && s < bidx)) { best = cd; bidx = s; blp = lp; }
            }
            #pragma unroll
            for (int off = 32; off >= 1; off >>= 1) {
                float ob = __shfl_xor(best, off, 64);
                int   oi = __shfl_xor(bidx, off, 64);
                float ol = __shfl_xor(blp, off, 64);
                if (ob > best || (ob == best && oi < bidx)) { best = ob; bidx = oi; blp = ol; }
            }
            lps += blp;
            if (lane == 0) {
                selA[w] = bidx;
                if (q == 0) out[(size_t)(g * 8 + w) * SN + t] = (float)bidx;
            }
        }
        __syncthreads();
        // ---- mask update + next-step xpro gather ----
        if (tid < 256) {
            int ss = tid >> 3, sl = tid & 7;
            if (selA[sl] == q * 32 + ss) mask[ss * 8 + sl] = -INFINITY;
        }
        {
            int sl = tid >> 6, rl = tid & 63;
            int rg = ((rl >> 4) << 8) + q * 16 + (rl & 15);
            xpro[sl * 64 + rl] = xprojG[(size_t)selA[sl] * 1024 + rg];
        }
        __syncthreads();
    }
    if (q == 0 && lane == 0) out[(size_t)BN * SN + g * 8 + w] = lps;
}

extern "C" void kernel_launch(void* const* d_in, const int* in_sizes, int n_in,
                              void* d_out, int out_size, void* d_ws, size_t ws_size,
                              hipStream_t stream)
{
    const float* x    = (const float*)d_in[0];
    const float* gmb  = (const float*)d_in[1];
    const float* Wih  = (const float*)d_in[2];
    const float* Whh  = (const float*)d_in[3];
    const float* bih  = (const float*)d_in[4];
    const float* bhh  = (const float*)d_in[5];
    const float* Wad  = (const float*)d_in[6];
    const float* Wae  = (const float*)d_in[7];
    const float* ba   = (const float*)d_in[8];
    const float* vvec = (const float*)d_in[9];
    const float* idec = (const float*)d_in[10];
    float* ws = (float*)d_ws;
    float* out = (float*)d_out;

    hipFuncSetAttribute(reinterpret_cast<const void*>(k_decode),
                        hipFuncAttributeMaxDynamicSharedMemorySize, SMEM_TOTAL);

    hipLaunchKernelGGL(k_init_transpose, dim3(4612), dim3(256), 0, stream,
                       Wih, bih, bhh, x, ws);
    hipLaunchKernelGGL(k_init_proj, dim3(1282), dim3(512), 0, stream,
                       x, Wae, ba, idec, ws);
    hipLaunchKernelGGL(k_decode, dim3(256), dim3(512), SMEM_TOTAL, stream,
                       gmb, vvec, Whh, Wad, ws, out);
}